// Round 12
// baseline (667.346 us; speedup 1.0000x reference)
//
#include <hip/hip_runtime.h>
#include <hip/hip_fp16.h>
#include <math.h>

#define N_NODES   100000
#define N_EDGES   1600000
#define N_FEAT    64
#define HIDDEN    64
#define BIOPRINT  2048
#define N_GRAPHS  1024

#define SCAN_BLK  1024
#define N_SCAN_BLOCKS ((N_NODES + SCAN_BLK - 1) / SCAN_BLK)   // 98
#define FILL_SLICE 50000                                       // 2 passes

typedef __attribute__((ext_vector_type(2))) _Float16 h2_t;
union H2 { int i; h2_t h; };

__device__ __forceinline__ __half2 shx_h2(__half2 v, int m) {
    int x = __shfl_xor(*(int*)&v, m);
    return *(__half2*)&x;
}

// ---------------- degree ----------------

__global__ void k_deg(const int* __restrict__ dst, int* __restrict__ deg, int n) {
    int i = blockIdx.x * blockDim.x + threadIdx.x;
    if (i < n) atomicAdd(&deg[__builtin_nontemporal_load(&dst[i])], 1);
}

// ---------------- weight transpose prep: Wt[n][k] = fp16(W[k][n]) ----------------
__global__ void k_prep(const float* __restrict__ W2, const float* __restrict__ W3,
                       __half* __restrict__ Wt2, __half* __restrict__ Wt3) {
    int idx = blockIdx.x * blockDim.x + threadIdx.x;   // 0..8191
    const float* W = (idx < 4096) ? W2 : W3;
    __half* Wt = (idx < 4096) ? Wt2 : Wt3;
    int e = idx & 4095;
    int n = e >> 6, k = e & 63;
    Wt[n * 64 + k] = __float2half_rn(W[k * 64 + n]);
}

// ---------------- CSR build: scan1 (+dinv), scan3 (+inline bsum scan, +gstart) ----------------

__global__ __launch_bounds__(SCAN_BLK) void k_scan1(
        const int* __restrict__ deg, int* __restrict__ incl,
        int* __restrict__ bsum, float* __restrict__ dinv, int n) {
    __shared__ int tmp[SCAN_BLK];
    int t = threadIdx.x;
    int i = blockIdx.x * SCAN_BLK + t;
    int v = (i < n) ? deg[i] : 0;
    if (i < n) dinv[i] = rsqrtf((float)v + 1.0f);
    tmp[t] = v;
    __syncthreads();
    for (int off = 1; off < SCAN_BLK; off <<= 1) {
        int u = (t >= off) ? tmp[t - off] : 0;
        __syncthreads();
        tmp[t] += u;
        __syncthreads();
    }
    if (i < n) incl[i] = tmp[t];
    if (t == SCAN_BLK - 1) bsum[blockIdx.x] = tmp[t];
}

__global__ __launch_bounds__(SCAN_BLK) void k_scan3(
        int* __restrict__ rowptr, const int* __restrict__ deg,
        const int* __restrict__ bsum, int* __restrict__ cursor,
        const int* __restrict__ batch, int* __restrict__ gstart, int n) {
    int t = threadIdx.x;
    int bid = blockIdx.x;
    if (bid >= N_SCAN_BLOCKS) {
        int g = (bid - N_SCAN_BLOCKS) * SCAN_BLK + t;
        if (g > N_GRAPHS) return;
        if (g == N_GRAPHS) { gstart[g] = N_NODES; return; }
        int lo = 0, hi = N_NODES;
        while (lo < hi) { int mid = (lo + hi) >> 1; if (batch[mid] < g) lo = mid + 1; else hi = mid; }
        gstart[g] = lo;
        return;
    }
    __shared__ int sb[128];
    if (t < 128) sb[t] = (t < N_SCAN_BLOCKS) ? bsum[t] : 0;
    __syncthreads();
    for (int off = 1; off < 128; off <<= 1) {
        int u = (t >= off && t < 128) ? sb[t - off] : 0;
        __syncthreads();
        if (t < 128) sb[t] += u;
        __syncthreads();
    }
    int base = (bid == 0) ? 0 : sb[bid - 1];
    int i = bid * SCAN_BLK + t;
    if (i < n) {
        int ex = rowptr[i] - deg[i] + base;
        rowptr[i] = ex;
        cursor[i] = ex;
    }
    if (i == 0) rowptr[n] = N_EDGES;
}

__global__ void k_fillp(const int* __restrict__ src, const int* __restrict__ dst,
                        int* __restrict__ cursor, int* __restrict__ col,
                        int lo, int hi, int n) {
    int e = blockIdx.x * blockDim.x + threadIdx.x;
    if (e < n) {
        int d = __builtin_nontemporal_load(&dst[e]);
        if (d >= lo && d < hi) {
            int s = __builtin_nontemporal_load(&src[e]);
            int pos = atomicAdd(&cursor[d], 1);
            col[pos] = s;
        }
    }
}

// ---------------- layer-1 matmul: hw1' = fp16[(x @ W1) * dinv] ----------------
__global__ __launch_bounds__(256) void k_mm(
        const float* __restrict__ h, const float* __restrict__ W,
        const float* __restrict__ dinv, __half* __restrict__ hw) {
    __shared__ float sW[64 * 64];
    __shared__ float sH[4 * 64];
    int t = threadIdx.x;
    const float4* W4 = (const float4*)W;
    float4* sW4 = (float4*)sW;
    for (int i = t; i < 1024; i += 256) sW4[i] = W4[i];
    int row0 = blockIdx.x * 4;
    int r = t >> 6, j = t & 63;
    sH[r * 64 + j] = h[(row0 + r) * 64 + j];
    __syncthreads();
    int i = row0 + r;
    float sum = 0.0f;
#pragma unroll
    for (int k = 0; k < 64; ++k) sum = fmaf(sH[r * 64 + k], sW[k * 64 + j], sum);
    hw[i * 64 + j] = __float2half_rn(sum * dinv[i]);
}

// ---------------- gather core: 8 lanes/row, fp16 pk accumulate ----------------
// After the xor-butterfly, ALL lanes hold the 8 features of chunk sub=lane&7.
__device__ __forceinline__ void gather8(
        const int* __restrict__ col, const uint4* __restrict__ hv,
        int rs, int re, int oct, int sub, float f[8]) {
    __half2 a0 = __float2half2_rn(0.f), a1 = a0, a2 = a0, a3 = a0;
    __half2 c0 = a0, c1 = a0, c2 = a0, c3 = a0;
    int e = rs;
    for (; e + 16 <= re; e += 16) {
        int s0 = __builtin_nontemporal_load(&col[e + oct]);
        int s1 = __builtin_nontemporal_load(&col[e + 8 + oct]);
        uint4 u0 = hv[(size_t)s0 * 8 + sub];
        uint4 u1 = hv[(size_t)s1 * 8 + sub];
        a0 = __hadd2(a0, *(__half2*)&u0.x); a1 = __hadd2(a1, *(__half2*)&u0.y);
        a2 = __hadd2(a2, *(__half2*)&u0.z); a3 = __hadd2(a3, *(__half2*)&u0.w);
        c0 = __hadd2(c0, *(__half2*)&u1.x); c1 = __hadd2(c1, *(__half2*)&u1.y);
        c2 = __hadd2(c2, *(__half2*)&u1.z); c3 = __hadd2(c3, *(__half2*)&u1.w);
    }
    if (e + 8 <= re) {
        int s0 = __builtin_nontemporal_load(&col[e + oct]);
        uint4 u0 = hv[(size_t)s0 * 8 + sub];
        a0 = __hadd2(a0, *(__half2*)&u0.x); a1 = __hadd2(a1, *(__half2*)&u0.y);
        a2 = __hadd2(a2, *(__half2*)&u0.z); a3 = __hadd2(a3, *(__half2*)&u0.w);
        e += 8;
    }
    if (e + oct < re) {
        int s0 = col[e + oct];
        uint4 u0 = hv[(size_t)s0 * 8 + sub];
        c0 = __hadd2(c0, *(__half2*)&u0.x); c1 = __hadd2(c1, *(__half2*)&u0.y);
        c2 = __hadd2(c2, *(__half2*)&u0.z); c3 = __hadd2(c3, *(__half2*)&u0.w);
    }
    a0 = __hadd2(a0, c0); a1 = __hadd2(a1, c1);
    a2 = __hadd2(a2, c2); a3 = __hadd2(a3, c3);
#pragma unroll
    for (int st = 8; st <= 32; st <<= 1) {
        a0 = __hadd2(a0, shx_h2(a0, st));
        a1 = __hadd2(a1, shx_h2(a1, st));
        a2 = __hadd2(a2, shx_h2(a2, st));
        a3 = __hadd2(a3, shx_h2(a3, st));
    }
    float2 f0 = __half22float2(a0), f1 = __half22float2(a1);
    float2 f2 = __half22float2(a2), f3 = __half22float2(a3);
    f[0] = f0.x; f[1] = f0.y; f[2] = f1.x; f[3] = f1.y;
    f[4] = f2.x; f[5] = f2.y; f[6] = f3.x; f[7] = f3.y;
}

// ---------------- fused gather + relu + register-W matmul (ZERO LDS/barriers) ----------------
// Wave = node. Lane j holds W column j in 8 uint4 regs (preloaded, L2-hot).
// After gather, lane c (c=0..7) holds conv chunk c packed as 4 half2 (pk[]);
// mm = 32 readlane broadcasts + 32 v_dot2_f32_f16, fp32 accumulate.
__global__ __launch_bounds__(256) void k_gmm(
        const int* __restrict__ rowptr, const int* __restrict__ col,
        const float* __restrict__ dinv, const float* __restrict__ b,
        const __half* __restrict__ hw_in, const __half* __restrict__ Wt,
        __half* __restrict__ hw_out) {
    int t = threadIdx.x;
    int wave = t >> 6, lane = t & 63;
    int oct = lane >> 3, sub = lane & 7;
    int i = blockIdx.x * 4 + wave;
    float di = dinv[i];
    int rs = rowptr[i], re = rowptr[i + 1];
    const uint4* hv = (const uint4*)hw_in;

    // preload W column `lane` (Wt row lane, 128B) — latency hidden by the gather
    const uint4* Wt4 = (const uint4*)Wt;
    uint4 wreg[8];
#pragma unroll
    for (int q = 0; q < 8; ++q) wreg[q] = Wt4[lane * 8 + q];

    float f[8];
    gather8(col, hv, rs, re, oct, sub, f);

    // conv epilogue (fp32): r = relu(di*(f+self)+b), packed to 4 half2
    uint4 us = hv[(size_t)i * 8 + sub];
    float2 s0 = __half22float2(*(__half2*)&us.x);
    float2 s1 = __half22float2(*(__half2*)&us.y);
    float2 s2 = __half22float2(*(__half2*)&us.z);
    float2 s3 = __half22float2(*(__half2*)&us.w);
    float sf[8] = {s0.x, s0.y, s1.x, s1.y, s2.x, s2.y, s3.x, s3.y};
    float4 ba = ((const float4*)b)[sub * 2];
    float4 bb = ((const float4*)b)[sub * 2 + 1];
    float bf[8] = {ba.x, ba.y, ba.z, ba.w, bb.x, bb.y, bb.z, bb.w};
    int pk[4];
#pragma unroll
    for (int c = 0; c < 4; ++c) {
        float r0 = fmaxf(fmaf(di, f[2 * c] + sf[2 * c], bf[2 * c]), 0.f);
        float r1 = fmaxf(fmaf(di, f[2 * c + 1] + sf[2 * c + 1], bf[2 * c + 1]), 0.f);
        __half2 h = __halves2half2(__float2half_rn(r0), __float2half_rn(r1));
        pk[c] = *(int*)&h;
    }

    // mm: out[lane] = sum_k a[k] * W[k][lane]  (a chunk c lives on lane c)
    float sum = 0.f;
#pragma unroll
    for (int c = 0; c < 8; ++c) {
        const int* wc = (const int*)&wreg[c];
#pragma unroll
        for (int d = 0; d < 4; ++d) {
            H2 a, w;
            a.i = __builtin_amdgcn_readlane(pk[d], c);
            w.i = wc[d];
            sum = __builtin_amdgcn_fdot2(a.h, w.h, sum, false);
        }
    }
    hw_out[(size_t)i * 64 + lane] = __float2half_rn(sum * di);   // pre-scale next layer
}

// ---------------- layer-3 gather (fp16 in, fp32 conv out) ----------------
__global__ __launch_bounds__(256) void k_gather3(
        const int* __restrict__ rowptr, const int* __restrict__ col,
        const float* __restrict__ dinv, const float* __restrict__ b,
        const __half* __restrict__ hw_in, float* __restrict__ conv) {
    int t = threadIdx.x;
    int wave = t >> 6, lane = t & 63;
    int oct = lane >> 3, sub = lane & 7;
    int i = blockIdx.x * 4 + wave;
    float di = dinv[i];
    int rs = rowptr[i], re = rowptr[i + 1];
    const uint4* hv = (const uint4*)hw_in;

    float f[8];
    gather8(col, hv, rs, re, oct, sub, f);

    if (oct == 0) {
        uint4 us = hv[(size_t)i * 8 + sub];
        float2 s0 = __half22float2(*(__half2*)&us.x);
        float2 s1 = __half22float2(*(__half2*)&us.y);
        float2 s2 = __half22float2(*(__half2*)&us.z);
        float2 s3 = __half22float2(*(__half2*)&us.w);
        float sf[8] = {s0.x, s0.y, s1.x, s1.y, s2.x, s2.y, s3.x, s3.y};
        float4 ba = ((const float4*)b)[sub * 2];
        float4 bb = ((const float4*)b)[sub * 2 + 1];
        float bf[8] = {ba.x, ba.y, ba.z, ba.w, bb.x, bb.y, bb.z, bb.w};
        float r[8];
#pragma unroll
        for (int k = 0; k < 8; ++k) r[k] = fmaf(di, f[k] + sf[k], bf[k]);
        *(float4*)&conv[(size_t)i * 64 + sub * 8]     = make_float4(r[0], r[1], r[2], r[3]);
        *(float4*)&conv[(size_t)i * 64 + sub * 8 + 4] = make_float4(r[4], r[5], r[6], r[7]);
    }
}

// ---------------- segmented mean-pool ----------------
__global__ __launch_bounds__(256) void k_pool(
        const float* __restrict__ conv, const int* __restrict__ gstart,
        float* __restrict__ pooled) {
    int t = threadIdx.x;
    int wave = t >> 6, lane = t & 63;
    int g = blockIdx.x * 4 + wave;
    int n0 = gstart[g], n1 = gstart[g + 1];
    float acc = 0.f;
    for (int i = n0; i < n1; ++i) acc += conv[(size_t)i * 64 + lane];
    int n = n1 - n0;
    pooled[g * 64 + lane] = (n > 0) ? acc / (float)n : 0.f;
}

// ---------------- dense + softmax + threshold: 8 graphs per block ----------------
__global__ __launch_bounds__(256) void k_dense(
        const float* __restrict__ pooled, const float* __restrict__ Wd,
        const float* __restrict__ bd, float* __restrict__ out) {
    __shared__ float sp[8][64];
    __shared__ float red[8][4];
    int t = threadIdx.x;
    int g0 = blockIdx.x * 8;
    for (int idx = t; idx < 512; idx += 256) {
        int g = idx >> 6, k = idx & 63;
        sp[g][k] = pooled[(g0 + g) * 64 + k];
    }
    __syncthreads();

    float acc[8][8];
#pragma unroll
    for (int r = 0; r < 8; ++r) {
        float bv = bd[r * 256 + t];
#pragma unroll
        for (int g = 0; g < 8; ++g) acc[g][r] = bv;
    }
    for (int k = 0; k < 64; ++k) {
        float w[8];
#pragma unroll
        for (int r = 0; r < 8; ++r) w[r] = Wd[k * BIOPRINT + r * 256 + t];
#pragma unroll
        for (int g = 0; g < 8; ++g) {
            float h = sp[g][k];
#pragma unroll
            for (int r = 0; r < 8; ++r) acc[g][r] = fmaf(h, w[r], acc[g][r]);
        }
    }
    int wave = t >> 6, lane = t & 63;
    float gm[8];
#pragma unroll
    for (int g = 0; g < 8; ++g) {
        float m = acc[g][0];
#pragma unroll
        for (int r = 1; r < 8; ++r) m = fmaxf(m, acc[g][r]);
#pragma unroll
        for (int off = 32; off > 0; off >>= 1) m = fmaxf(m, __shfl_xor(m, off));
        if (lane == 0) red[g][wave] = m;
    }
    __syncthreads();
#pragma unroll
    for (int g = 0; g < 8; ++g)
        gm[g] = fmaxf(fmaxf(red[g][0], red[g][1]), fmaxf(red[g][2], red[g][3]));
    __syncthreads();
    float gs[8];
#pragma unroll
    for (int g = 0; g < 8; ++g) {
        float s = 0.f;
#pragma unroll
        for (int r = 0; r < 8; ++r) { acc[g][r] = expf(acc[g][r] - gm[g]); s += acc[g][r]; }
#pragma unroll
        for (int off = 32; off > 0; off >>= 1) s += __shfl_xor(s, off);
        if (lane == 0) red[g][wave] = s;
    }
    __syncthreads();
#pragma unroll
    for (int g = 0; g < 8; ++g)
        gs[g] = red[g][0] + red[g][1] + red[g][2] + red[g][3];
#pragma unroll
    for (int g = 0; g < 8; ++g)
#pragma unroll
        for (int r = 0; r < 8; ++r) {
            float p = acc[g][r] / gs[g];
            out[(size_t)(g0 + g) * BIOPRINT + r * 256 + t] = (p >= 0.5f) ? 1.0f : 0.0f;
        }
}

// ---------------- launch ----------------

extern "C" void kernel_launch(void* const* d_in, const int* in_sizes, int n_in,
                              void* d_out, int out_size, void* d_ws, size_t ws_size,
                              hipStream_t stream) {
    const float* x     = (const float*)d_in[0];
    const int*   ei    = (const int*)d_in[1];
    const int*   batch = (const int*)d_in[2];
    const float* W1 = (const float*)d_in[3];
    const float* b1 = (const float*)d_in[4];
    const float* W2 = (const float*)d_in[5];
    const float* b2 = (const float*)d_in[6];
    const float* W3 = (const float*)d_in[7];
    const float* b3 = (const float*)d_in[8];
    const float* Wd = (const float*)d_in[9];
    const float* bd = (const float*)d_in[10];
    float* out = (float*)d_out;

    const int* src = ei;
    const int* dst = ei + N_EDGES;

    char* ws = (char*)d_ws;
    size_t off = 0;
    auto alloc = [&](size_t bytes) {
        void* p = ws + off;
        off += (bytes + 255) & ~(size_t)255;
        return p;
    };
    int*    deg    = (int*)alloc(N_NODES * sizeof(int));
    float*  dinv   = (float*)alloc(N_NODES * sizeof(float));
    float*  pooled = (float*)alloc(N_GRAPHS * HIDDEN * sizeof(float));
    int*    rowptr = (int*)alloc((N_NODES + 1) * sizeof(int));
    int*    bsum   = (int*)alloc(128 * sizeof(int));
    int*    cursor = (int*)alloc(N_NODES * sizeof(int));
    int*    gstart = (int*)alloc((N_GRAPHS + 1) * sizeof(int));
    int*    col    = (int*)alloc((size_t)N_EDGES * sizeof(int));
    __half* Wt2    = (__half*)alloc(64 * 64 * sizeof(__half));
    __half* Wt3    = (__half*)alloc(64 * 64 * sizeof(__half));
    __half* bufA   = (__half*)alloc((size_t)N_NODES * HIDDEN * sizeof(__half));
    __half* bufB   = (__half*)alloc((size_t)N_NODES * HIDDEN * sizeof(__half));
    float*  conv   = (float*)alloc((size_t)N_NODES * HIDDEN * sizeof(float));

    hipMemsetAsync(deg, 0, N_NODES * sizeof(int), stream);

    k_prep<<<32, 256, 0, stream>>>(W2, W3, Wt2, Wt3);
    k_deg<<<(N_EDGES + 255) / 256, 256, 0, stream>>>(dst, deg, N_EDGES);
    k_scan1<<<N_SCAN_BLOCKS, SCAN_BLK, 0, stream>>>(deg, rowptr, bsum, dinv, N_NODES);
    k_scan3<<<N_SCAN_BLOCKS + 2, SCAN_BLK, 0, stream>>>(rowptr, deg, bsum, cursor,
                                                        batch, gstart, N_NODES);
    for (int p = 0; p < 2; ++p) {
        k_fillp<<<(N_EDGES + 255) / 256, 256, 0, stream>>>(
            src, dst, cursor, col, p * FILL_SLICE, (p + 1) * FILL_SLICE, N_EDGES);
    }

    const int mm_grid = N_NODES / 4;          // 25000
    k_mm<<<mm_grid, 256, 0, stream>>>(x, W1, dinv, bufA);
    k_gmm<<<mm_grid, 256, 0, stream>>>(rowptr, col, dinv, b1, bufA, Wt2, bufB);
    k_gmm<<<mm_grid, 256, 0, stream>>>(rowptr, col, dinv, b2, bufB, Wt3, bufA);
    k_gather3<<<mm_grid, 256, 0, stream>>>(rowptr, col, dinv, b3, bufA, conv);
    k_pool<<<N_GRAPHS / 4, 256, 0, stream>>>(conv, gstart, pooled);
    k_dense<<<N_GRAPHS / 8, 256, 0, stream>>>(pooled, Wd, bd, out);
}

// Round 13
// 551.301 us; speedup vs baseline: 1.2105x; 1.2105x over previous
//
#include <hip/hip_runtime.h>
#include <hip/hip_fp16.h>
#include <math.h>

#define N_NODES   100000
#define N_EDGES   1600000
#define N_FEAT    64
#define HIDDEN    64
#define BIOPRINT  2048
#define N_GRAPHS  1024

#define SCAN_BLK  1024
#define N_SCAN_BLOCKS ((N_NODES + SCAN_BLK - 1) / SCAN_BLK)   // 98
#define FILL_SLICE 50000                                       // 2 passes

__device__ __forceinline__ __half2 shx_h2(__half2 v, int m) {
    int x = __shfl_xor(*(int*)&v, m);
    return *(__half2*)&x;
}

// ---------------- degree ----------------

__global__ void k_deg(const int* __restrict__ dst, int* __restrict__ deg, int n) {
    int i = blockIdx.x * blockDim.x + threadIdx.x;
    if (i < n) atomicAdd(&deg[__builtin_nontemporal_load(&dst[i])], 1);
}

// ---------------- CSR build: scan1 (+dinv), scan3 (+inline bsum scan, +gstart) ----------------

__global__ __launch_bounds__(SCAN_BLK) void k_scan1(
        const int* __restrict__ deg, int* __restrict__ incl,
        int* __restrict__ bsum, float* __restrict__ dinv, int n) {
    __shared__ int tmp[SCAN_BLK];
    int t = threadIdx.x;
    int i = blockIdx.x * SCAN_BLK + t;
    int v = (i < n) ? deg[i] : 0;
    if (i < n) dinv[i] = rsqrtf((float)v + 1.0f);
    tmp[t] = v;
    __syncthreads();
    for (int off = 1; off < SCAN_BLK; off <<= 1) {
        int u = (t >= off) ? tmp[t - off] : 0;
        __syncthreads();
        tmp[t] += u;
        __syncthreads();
    }
    if (i < n) incl[i] = tmp[t];
    if (t == SCAN_BLK - 1) bsum[blockIdx.x] = tmp[t];
}

__global__ __launch_bounds__(SCAN_BLK) void k_scan3(
        int* __restrict__ rowptr, const int* __restrict__ deg,
        const int* __restrict__ bsum, int* __restrict__ cursor,
        const int* __restrict__ batch, int* __restrict__ gstart, int n) {
    int t = threadIdx.x;
    int bid = blockIdx.x;
    if (bid >= N_SCAN_BLOCKS) {
        int g = (bid - N_SCAN_BLOCKS) * SCAN_BLK + t;
        if (g > N_GRAPHS) return;
        if (g == N_GRAPHS) { gstart[g] = N_NODES; return; }
        int lo = 0, hi = N_NODES;
        while (lo < hi) { int mid = (lo + hi) >> 1; if (batch[mid] < g) lo = mid + 1; else hi = mid; }
        gstart[g] = lo;
        return;
    }
    __shared__ int sb[128];
    if (t < 128) sb[t] = (t < N_SCAN_BLOCKS) ? bsum[t] : 0;
    __syncthreads();
    for (int off = 1; off < 128; off <<= 1) {
        int u = (t >= off && t < 128) ? sb[t - off] : 0;
        __syncthreads();
        if (t < 128) sb[t] += u;
        __syncthreads();
    }
    int base = (bid == 0) ? 0 : sb[bid - 1];
    int i = bid * SCAN_BLK + t;
    if (i < n) {
        int ex = rowptr[i] - deg[i] + base;
        rowptr[i] = ex;
        cursor[i] = ex;
    }
    if (i == 0) rowptr[n] = N_EDGES;
}

__global__ void k_fillp(const int* __restrict__ src, const int* __restrict__ dst,
                        int* __restrict__ cursor, int* __restrict__ col,
                        int lo, int hi, int n) {
    int e = blockIdx.x * blockDim.x + threadIdx.x;
    if (e < n) {
        int d = __builtin_nontemporal_load(&dst[e]);
        if (d >= lo && d < hi) {
            int s = __builtin_nontemporal_load(&src[e]);
            int pos = atomicAdd(&cursor[d], 1);
            col[pos] = s;
        }
    }
}

// ---------------- layer-1 matmul: hw1' = fp16[(x @ W1) * dinv] ----------------
__global__ __launch_bounds__(256) void k_mm(
        const float* __restrict__ h, const float* __restrict__ W,
        const float* __restrict__ dinv, __half* __restrict__ hw) {
    __shared__ float sW[64 * 64];
    __shared__ float sH[4 * 64];
    int t = threadIdx.x;
    const float4* W4 = (const float4*)W;
    float4* sW4 = (float4*)sW;
    for (int i = t; i < 1024; i += 256) sW4[i] = W4[i];
    int row0 = blockIdx.x * 4;
    int r = t >> 6, j = t & 63;
    sH[r * 64 + j] = h[(row0 + r) * 64 + j];
    __syncthreads();
    int i = row0 + r;
    float sum = 0.0f;
#pragma unroll
    for (int k = 0; k < 64; ++k) sum = fmaf(sH[r * 64 + k], sW[k * 64 + j], sum);
    hw[i * 64 + j] = __float2half_rn(sum * dinv[i]);
}

// ---------------- gather core: 2 nodes per wave, 4 slots/node, fp16 pk accumulate ----------------
// Lane = half*32 + slot*8 + sub. The two 32-lane halves gather DIFFERENT nodes
// -> two independent col->row load chains per wave (2x memory-level parallelism).
// After the 2-stage butterfly (xor 8,16 — stays inside the half), every lane of
// a half holds the 8 features of chunk sub for its node.
__device__ __forceinline__ void gather4(
        const int* __restrict__ col, const uint4* __restrict__ hv,
        int rs, int re, int slot, int sub, float f[8]) {
    __half2 a0 = __float2half2_rn(0.f), a1 = a0, a2 = a0, a3 = a0;
    __half2 c0 = a0, c1 = a0, c2 = a0, c3 = a0;
    int e = rs;
    for (; e + 8 <= re; e += 8) {
        int s0 = __builtin_nontemporal_load(&col[e + slot]);
        int s1 = __builtin_nontemporal_load(&col[e + 4 + slot]);
        uint4 u0 = hv[(size_t)s0 * 8 + sub];
        uint4 u1 = hv[(size_t)s1 * 8 + sub];
        a0 = __hadd2(a0, *(__half2*)&u0.x); a1 = __hadd2(a1, *(__half2*)&u0.y);
        a2 = __hadd2(a2, *(__half2*)&u0.z); a3 = __hadd2(a3, *(__half2*)&u0.w);
        c0 = __hadd2(c0, *(__half2*)&u1.x); c1 = __hadd2(c1, *(__half2*)&u1.y);
        c2 = __hadd2(c2, *(__half2*)&u1.z); c3 = __hadd2(c3, *(__half2*)&u1.w);
    }
    if (e + 4 <= re) {
        int s0 = __builtin_nontemporal_load(&col[e + slot]);
        uint4 u0 = hv[(size_t)s0 * 8 + sub];
        a0 = __hadd2(a0, *(__half2*)&u0.x); a1 = __hadd2(a1, *(__half2*)&u0.y);
        a2 = __hadd2(a2, *(__half2*)&u0.z); a3 = __hadd2(a3, *(__half2*)&u0.w);
        e += 4;
    }
    if (e + slot < re) {
        int s0 = col[e + slot];
        uint4 u0 = hv[(size_t)s0 * 8 + sub];
        c0 = __hadd2(c0, *(__half2*)&u0.x); c1 = __hadd2(c1, *(__half2*)&u0.y);
        c2 = __hadd2(c2, *(__half2*)&u0.z); c3 = __hadd2(c3, *(__half2*)&u0.w);
    }
    a0 = __hadd2(a0, c0); a1 = __hadd2(a1, c1);
    a2 = __hadd2(a2, c2); a3 = __hadd2(a3, c3);
#pragma unroll
    for (int st = 8; st <= 16; st <<= 1) {
        a0 = __hadd2(a0, shx_h2(a0, st));
        a1 = __hadd2(a1, shx_h2(a1, st));
        a2 = __hadd2(a2, shx_h2(a2, st));
        a3 = __hadd2(a3, shx_h2(a3, st));
    }
    float2 f0 = __half22float2(a0), f1 = __half22float2(a1);
    float2 f2 = __half22float2(a2), f3 = __half22float2(a3);
    f[0] = f0.x; f[1] = f0.y; f[2] = f1.x; f[3] = f1.y;
    f[4] = f2.x; f[5] = f2.y; f[6] = f3.x; f[7] = f3.y;
}

// ---------------- fused gather(2 nodes/wave) + relu + LDS matmul ----------------
// Block = 4 waves = 8 nodes. R9's proven LDS mm epilogue, now 2 rows per wave.
__global__ __launch_bounds__(256) void k_gmm(
        const int* __restrict__ rowptr, const int* __restrict__ col,
        const float* __restrict__ dinv, const float* __restrict__ b,
        const __half* __restrict__ hw_in, const float* __restrict__ W,
        __half* __restrict__ hw_out) {
    __shared__ float sW[64 * 64];
    __shared__ float sA[8 * 64];
    int t = threadIdx.x;
    const float4* W4 = (const float4*)W;
    float4* sW4 = (float4*)sW;
    for (int i = t; i < 1024; i += 256) sW4[i] = W4[i];
    __syncthreads();

    int wave = t >> 6, lane = t & 63;
    int half = lane >> 5, slot = (lane >> 3) & 3, sub = lane & 7;
    int i0 = blockIdx.x * 8 + wave * 2;
    int i = i0 + half;
    float di = dinv[i];
    int rs = rowptr[i], re = rowptr[i + 1];
    const uint4* hv = (const uint4*)hw_in;

    float f[8];
    gather4(col, hv, rs, re, slot, sub, f);

    // conv epilogue (fp32): r = relu(di*(f+self)+b)
    uint4 us = hv[(size_t)i * 8 + sub];
    float2 s0 = __half22float2(*(__half2*)&us.x);
    float2 s1 = __half22float2(*(__half2*)&us.y);
    float2 s2 = __half22float2(*(__half2*)&us.z);
    float2 s3 = __half22float2(*(__half2*)&us.w);
    float sf[8] = {s0.x, s0.y, s1.x, s1.y, s2.x, s2.y, s3.x, s3.y};
    float4 ba = ((const float4*)b)[sub * 2];
    float4 bb = ((const float4*)b)[sub * 2 + 1];
    float bf[8] = {ba.x, ba.y, ba.z, ba.w, bb.x, bb.y, bb.z, bb.w};
    if (slot == 0) {
        float r[8];
#pragma unroll
        for (int k = 0; k < 8; ++k) r[k] = fmaxf(fmaf(di, f[k] + sf[k], bf[k]), 0.f);
        *(float4*)&sA[(wave * 2 + half) * 64 + sub * 8]     = make_float4(r[0], r[1], r[2], r[3]);
        *(float4*)&sA[(wave * 2 + half) * 64 + sub * 8 + 4] = make_float4(r[4], r[5], r[6], r[7]);
    }

    // per-wave mm for BOTH nodes (same-wave LDS ordering; barrier above covers sW)
    float d0 = dinv[i0], d1 = dinv[i0 + 1];
#pragma unroll
    for (int h = 0; h < 2; ++h) {
        const float4* sA4 = (const float4*)&sA[(wave * 2 + h) * 64];
        float sum = 0.f;
#pragma unroll
        for (int k4 = 0; k4 < 16; ++k4) {
            float4 a4 = sA4[k4];
            sum = fmaf(a4.x, sW[(k4 * 4 + 0) * 64 + lane], sum);
            sum = fmaf(a4.y, sW[(k4 * 4 + 1) * 64 + lane], sum);
            sum = fmaf(a4.z, sW[(k4 * 4 + 2) * 64 + lane], sum);
            sum = fmaf(a4.w, sW[(k4 * 4 + 3) * 64 + lane], sum);
        }
        float dh = h ? d1 : d0;
        hw_out[(size_t)(i0 + h) * 64 + lane] = __float2half_rn(sum * dh);
    }
}

// ---------------- layer-3 gather (2 nodes/wave; fp16 conv out) ----------------
__global__ __launch_bounds__(256) void k_gather3(
        const int* __restrict__ rowptr, const int* __restrict__ col,
        const float* __restrict__ dinv, const float* __restrict__ b,
        const __half* __restrict__ hw_in, __half* __restrict__ conv) {
    int t = threadIdx.x;
    int wave = t >> 6, lane = t & 63;
    int half = lane >> 5, slot = (lane >> 3) & 3, sub = lane & 7;
    int i = blockIdx.x * 8 + wave * 2 + half;
    float di = dinv[i];
    int rs = rowptr[i], re = rowptr[i + 1];
    const uint4* hv = (const uint4*)hw_in;

    float f[8];
    gather4(col, hv, rs, re, slot, sub, f);

    if (slot == 0) {
        uint4 us = hv[(size_t)i * 8 + sub];
        float2 s0 = __half22float2(*(__half2*)&us.x);
        float2 s1 = __half22float2(*(__half2*)&us.y);
        float2 s2 = __half22float2(*(__half2*)&us.z);
        float2 s3 = __half22float2(*(__half2*)&us.w);
        float sf[8] = {s0.x, s0.y, s1.x, s1.y, s2.x, s2.y, s3.x, s3.y};
        float4 ba = ((const float4*)b)[sub * 2];
        float4 bb = ((const float4*)b)[sub * 2 + 1];
        float bf[8] = {ba.x, ba.y, ba.z, ba.w, bb.x, bb.y, bb.z, bb.w};
        uint4 o;
        __half2* oh = (__half2*)&o;
#pragma unroll
        for (int c = 0; c < 4; ++c) {
            float r0 = fmaf(di, f[2 * c] + sf[2 * c], bf[2 * c]);
            float r1 = fmaf(di, f[2 * c + 1] + sf[2 * c + 1], bf[2 * c + 1]);
            oh[c] = __halves2half2(__float2half_rn(r0), __float2half_rn(r1));
        }
        ((uint4*)conv)[(size_t)i * 8 + sub] = o;
    }
}

// ---------------- segmented mean-pool (fp16 conv in) ----------------
__global__ __launch_bounds__(256) void k_pool(
        const __half* __restrict__ conv, const int* __restrict__ gstart,
        float* __restrict__ pooled) {
    int t = threadIdx.x;
    int wave = t >> 6, lane = t & 63;
    int g = blockIdx.x * 4 + wave;
    int n0 = gstart[g], n1 = gstart[g + 1];
    float acc = 0.f;
    for (int i = n0; i < n1; ++i) acc += __half2float(conv[(size_t)i * 64 + lane]);
    int n = n1 - n0;
    pooled[g * 64 + lane] = (n > 0) ? acc / (float)n : 0.f;
}

// ---------------- dense + softmax + threshold: 8 graphs per block ----------------
__global__ __launch_bounds__(256) void k_dense(
        const float* __restrict__ pooled, const float* __restrict__ Wd,
        const float* __restrict__ bd, float* __restrict__ out) {
    __shared__ float sp[8][64];
    __shared__ float red[8][4];
    int t = threadIdx.x;
    int g0 = blockIdx.x * 8;
    for (int idx = t; idx < 512; idx += 256) {
        int g = idx >> 6, k = idx & 63;
        sp[g][k] = pooled[(g0 + g) * 64 + k];
    }
    __syncthreads();

    float acc[8][8];
#pragma unroll
    for (int r = 0; r < 8; ++r) {
        float bv = bd[r * 256 + t];
#pragma unroll
        for (int g = 0; g < 8; ++g) acc[g][r] = bv;
    }
    for (int k = 0; k < 64; ++k) {
        float w[8];
#pragma unroll
        for (int r = 0; r < 8; ++r) w[r] = Wd[k * BIOPRINT + r * 256 + t];
#pragma unroll
        for (int g = 0; g < 8; ++g) {
            float h = sp[g][k];
#pragma unroll
            for (int r = 0; r < 8; ++r) acc[g][r] = fmaf(h, w[r], acc[g][r]);
        }
    }
    int wave = t >> 6, lane = t & 63;
    float gm[8];
#pragma unroll
    for (int g = 0; g < 8; ++g) {
        float m = acc[g][0];
#pragma unroll
        for (int r = 1; r < 8; ++r) m = fmaxf(m, acc[g][r]);
#pragma unroll
        for (int off = 32; off > 0; off >>= 1) m = fmaxf(m, __shfl_xor(m, off));
        if (lane == 0) red[g][wave] = m;
    }
    __syncthreads();
#pragma unroll
    for (int g = 0; g < 8; ++g)
        gm[g] = fmaxf(fmaxf(red[g][0], red[g][1]), fmaxf(red[g][2], red[g][3]));
    __syncthreads();
    float gs[8];
#pragma unroll
    for (int g = 0; g < 8; ++g) {
        float s = 0.f;
#pragma unroll
        for (int r = 0; r < 8; ++r) { acc[g][r] = expf(acc[g][r] - gm[g]); s += acc[g][r]; }
#pragma unroll
        for (int off = 32; off > 0; off >>= 1) s += __shfl_xor(s, off);
        if (lane == 0) red[g][wave] = s;
    }
    __syncthreads();
#pragma unroll
    for (int g = 0; g < 8; ++g)
        gs[g] = red[g][0] + red[g][1] + red[g][2] + red[g][3];
#pragma unroll
    for (int g = 0; g < 8; ++g)
#pragma unroll
        for (int r = 0; r < 8; ++r) {
            float p = acc[g][r] / gs[g];
            out[(size_t)(g0 + g) * BIOPRINT + r * 256 + t] = (p >= 0.5f) ? 1.0f : 0.0f;
        }
}

// ---------------- launch ----------------

extern "C" void kernel_launch(void* const* d_in, const int* in_sizes, int n_in,
                              void* d_out, int out_size, void* d_ws, size_t ws_size,
                              hipStream_t stream) {
    const float* x     = (const float*)d_in[0];
    const int*   ei    = (const int*)d_in[1];
    const int*   batch = (const int*)d_in[2];
    const float* W1 = (const float*)d_in[3];
    const float* b1 = (const float*)d_in[4];
    const float* W2 = (const float*)d_in[5];
    const float* b2 = (const float*)d_in[6];
    const float* W3 = (const float*)d_in[7];
    const float* b3 = (const float*)d_in[8];
    const float* Wd = (const float*)d_in[9];
    const float* bd = (const float*)d_in[10];
    float* out = (float*)d_out;

    const int* src = ei;
    const int* dst = ei + N_EDGES;

    char* ws = (char*)d_ws;
    size_t off = 0;
    auto alloc = [&](size_t bytes) {
        void* p = ws + off;
        off += (bytes + 255) & ~(size_t)255;
        return p;
    };
    int*    deg    = (int*)alloc(N_NODES * sizeof(int));
    float*  dinv   = (float*)alloc(N_NODES * sizeof(float));
    float*  pooled = (float*)alloc(N_GRAPHS * HIDDEN * sizeof(float));
    int*    rowptr = (int*)alloc((N_NODES + 1) * sizeof(int));
    int*    bsum   = (int*)alloc(128 * sizeof(int));
    int*    cursor = (int*)alloc(N_NODES * sizeof(int));
    int*    gstart = (int*)alloc((N_GRAPHS + 1) * sizeof(int));
    int*    col    = (int*)alloc((size_t)N_EDGES * sizeof(int));
    __half* bufA   = (__half*)alloc((size_t)N_NODES * HIDDEN * sizeof(__half));
    __half* bufB   = (__half*)alloc((size_t)N_NODES * HIDDEN * sizeof(__half));
    __half* conv   = (__half*)alloc((size_t)N_NODES * HIDDEN * sizeof(__half));

    hipMemsetAsync(deg, 0, N_NODES * sizeof(int), stream);

    k_deg<<<(N_EDGES + 255) / 256, 256, 0, stream>>>(dst, deg, N_EDGES);
    k_scan1<<<N_SCAN_BLOCKS, SCAN_BLK, 0, stream>>>(deg, rowptr, bsum, dinv, N_NODES);
    k_scan3<<<N_SCAN_BLOCKS + 2, SCAN_BLK, 0, stream>>>(rowptr, deg, bsum, cursor,
                                                        batch, gstart, N_NODES);
    for (int p = 0; p < 2; ++p) {
        k_fillp<<<(N_EDGES + 255) / 256, 256, 0, stream>>>(
            src, dst, cursor, col, p * FILL_SLICE, (p + 1) * FILL_SLICE, N_EDGES);
    }

    const int mm_grid = N_NODES / 4;          // 25000
    const int g8_grid = N_NODES / 8;          // 12500 (8 nodes/block)
    k_mm<<<mm_grid, 256, 0, stream>>>(x, W1, dinv, bufA);
    k_gmm<<<g8_grid, 256, 0, stream>>>(rowptr, col, dinv, b1, bufA, W2, bufB);
    k_gmm<<<g8_grid, 256, 0, stream>>>(rowptr, col, dinv, b2, bufB, W3, bufA);
    k_gather3<<<g8_grid, 256, 0, stream>>>(rowptr, col, dinv, b3, bufA, conv);
    k_pool<<<N_GRAPHS / 4, 256, 0, stream>>>(conv, gstart, pooled);
    k_dense<<<N_GRAPHS / 8, 256, 0, stream>>>(pooled, Wd, bd, out);
}

// Round 14
// 539.448 us; speedup vs baseline: 1.2371x; 1.0220x over previous
//
#include <hip/hip_runtime.h>
#include <hip/hip_fp16.h>
#include <math.h>

#define N_NODES   100000
#define N_EDGES   1600000
#define N_FEAT    64
#define HIDDEN    64
#define BIOPRINT  2048
#define N_GRAPHS  1024

#define SCAN_BLK  1024
#define N_SCAN_BLOCKS ((N_NODES + SCAN_BLK - 1) / SCAN_BLK)   // 98
#define FILL_SLICE 50000                                       // 2 passes

__device__ __forceinline__ __half2 shx_h2(__half2 v, int m) {
    int x = __shfl_xor(*(int*)&v, m);
    return *(__half2*)&x;
}

// ---------------- degree ----------------

__global__ void k_deg(const int* __restrict__ dst, int* __restrict__ deg, int n) {
    int i = blockIdx.x * blockDim.x + threadIdx.x;
    if (i < n) atomicAdd(&deg[__builtin_nontemporal_load(&dst[i])], 1);
}

// ---------------- CSR build: scan1 (+dinv), scan3 (+inline bsum scan, +gstart) ----------------

__global__ __launch_bounds__(SCAN_BLK) void k_scan1(
        const int* __restrict__ deg, int* __restrict__ incl,
        int* __restrict__ bsum, float* __restrict__ dinv, int n) {
    __shared__ int tmp[SCAN_BLK];
    int t = threadIdx.x;
    int i = blockIdx.x * SCAN_BLK + t;
    int v = (i < n) ? deg[i] : 0;
    if (i < n) dinv[i] = rsqrtf((float)v + 1.0f);
    tmp[t] = v;
    __syncthreads();
    for (int off = 1; off < SCAN_BLK; off <<= 1) {
        int u = (t >= off) ? tmp[t - off] : 0;
        __syncthreads();
        tmp[t] += u;
        __syncthreads();
    }
    if (i < n) incl[i] = tmp[t];
    if (t == SCAN_BLK - 1) bsum[blockIdx.x] = tmp[t];
}

__global__ __launch_bounds__(SCAN_BLK) void k_scan3(
        int* __restrict__ rowptr, const int* __restrict__ deg,
        const int* __restrict__ bsum, int* __restrict__ cursor,
        const int* __restrict__ batch, int* __restrict__ gstart, int n) {
    int t = threadIdx.x;
    int bid = blockIdx.x;
    if (bid >= N_SCAN_BLOCKS) {
        int g = (bid - N_SCAN_BLOCKS) * SCAN_BLK + t;
        if (g > N_GRAPHS) return;
        if (g == N_GRAPHS) { gstart[g] = N_NODES; return; }
        int lo = 0, hi = N_NODES;
        while (lo < hi) { int mid = (lo + hi) >> 1; if (batch[mid] < g) lo = mid + 1; else hi = mid; }
        gstart[g] = lo;
        return;
    }
    __shared__ int sb[128];
    if (t < 128) sb[t] = (t < N_SCAN_BLOCKS) ? bsum[t] : 0;
    __syncthreads();
    for (int off = 1; off < 128; off <<= 1) {
        int u = (t >= off && t < 128) ? sb[t - off] : 0;
        __syncthreads();
        if (t < 128) sb[t] += u;
        __syncthreads();
    }
    int base = (bid == 0) ? 0 : sb[bid - 1];
    int i = bid * SCAN_BLK + t;
    if (i < n) {
        int ex = rowptr[i] - deg[i] + base;
        rowptr[i] = ex;
        cursor[i] = ex;
    }
    if (i == 0) rowptr[n] = N_EDGES;
}

__global__ void k_fillp(const int* __restrict__ src, const int* __restrict__ dst,
                        int* __restrict__ cursor, int* __restrict__ col,
                        int lo, int hi, int n) {
    int e = blockIdx.x * blockDim.x + threadIdx.x;
    if (e < n) {
        int d = __builtin_nontemporal_load(&dst[e]);
        if (d >= lo && d < hi) {
            int s = __builtin_nontemporal_load(&src[e]);
            int pos = atomicAdd(&cursor[d], 1);
            col[pos] = s;
        }
    }
}

// ---------------- layer-1 matmul: hw1' = fp16[(x @ W1) * dinv] ----------------
__global__ __launch_bounds__(256) void k_mm(
        const float* __restrict__ h, const float* __restrict__ W,
        const float* __restrict__ dinv, __half* __restrict__ hw) {
    __shared__ float sW[64 * 64];
    __shared__ float sH[4 * 64];
    int t = threadIdx.x;
    const float4* W4 = (const float4*)W;
    float4* sW4 = (float4*)sW;
    for (int i = t; i < 1024; i += 256) sW4[i] = W4[i];
    int row0 = blockIdx.x * 4;
    int r = t >> 6, j = t & 63;
    sH[r * 64 + j] = h[(row0 + r) * 64 + j];
    __syncthreads();
    int i = row0 + r;
    float sum = 0.0f;
#pragma unroll
    for (int k = 0; k < 64; ++k) sum = fmaf(sH[r * 64 + k], sW[k * 64 + j], sum);
    hw[i * 64 + j] = __float2half_rn(sum * dinv[i]);
}

// ---------------- gather core: 4 nodes per wave, 2 slots/node, 4 loads in flight ----------------
// Lane = quarter*16 + slot*8 + sub. Four 16-lane quarters gather DIFFERENT nodes
// -> 4 independent col->row chains/wave; per iteration 4 independent hv loads
// per lane. 1-stage butterfly (xor 8) combines the two slots.
__device__ __forceinline__ void gather2x4(
        const int* __restrict__ col, const uint4* __restrict__ hv,
        int rs, int re, int slot, int sub, float f[8]) {
    __half2 a0 = __float2half2_rn(0.f), a1 = a0, a2 = a0, a3 = a0;
    __half2 c0 = a0, c1 = a0, c2 = a0, c3 = a0;
    int e = rs;
    for (; e + 8 <= re; e += 8) {
        int s0 = __builtin_nontemporal_load(&col[e + slot]);
        int s1 = __builtin_nontemporal_load(&col[e + 2 + slot]);
        int s2 = __builtin_nontemporal_load(&col[e + 4 + slot]);
        int s3 = __builtin_nontemporal_load(&col[e + 6 + slot]);
        uint4 u0 = hv[(size_t)s0 * 8 + sub];
        uint4 u1 = hv[(size_t)s1 * 8 + sub];
        uint4 u2 = hv[(size_t)s2 * 8 + sub];
        uint4 u3 = hv[(size_t)s3 * 8 + sub];
        a0 = __hadd2(a0, *(__half2*)&u0.x); a1 = __hadd2(a1, *(__half2*)&u0.y);
        a2 = __hadd2(a2, *(__half2*)&u0.z); a3 = __hadd2(a3, *(__half2*)&u0.w);
        c0 = __hadd2(c0, *(__half2*)&u1.x); c1 = __hadd2(c1, *(__half2*)&u1.y);
        c2 = __hadd2(c2, *(__half2*)&u1.z); c3 = __hadd2(c3, *(__half2*)&u1.w);
        a0 = __hadd2(a0, *(__half2*)&u2.x); a1 = __hadd2(a1, *(__half2*)&u2.y);
        a2 = __hadd2(a2, *(__half2*)&u2.z); a3 = __hadd2(a3, *(__half2*)&u2.w);
        c0 = __hadd2(c0, *(__half2*)&u3.x); c1 = __hadd2(c1, *(__half2*)&u3.y);
        c2 = __hadd2(c2, *(__half2*)&u3.z); c3 = __hadd2(c3, *(__half2*)&u3.w);
    }
    // tail: 2 edges per step (one per slot)
    for (; e + slot < re; e += 2) {
        int s0 = col[e + slot];
        uint4 u0 = hv[(size_t)s0 * 8 + sub];
        a0 = __hadd2(a0, *(__half2*)&u0.x); a1 = __hadd2(a1, *(__half2*)&u0.y);
        a2 = __hadd2(a2, *(__half2*)&u0.z); a3 = __hadd2(a3, *(__half2*)&u0.w);
    }
    a0 = __hadd2(a0, c0); a1 = __hadd2(a1, c1);
    a2 = __hadd2(a2, c2); a3 = __hadd2(a3, c3);
    // combine the two slots (lane ^ 8 stays inside the quarter)
    a0 = __hadd2(a0, shx_h2(a0, 8));
    a1 = __hadd2(a1, shx_h2(a1, 8));
    a2 = __hadd2(a2, shx_h2(a2, 8));
    a3 = __hadd2(a3, shx_h2(a3, 8));
    float2 f0 = __half22float2(a0), f1 = __half22float2(a1);
    float2 f2 = __half22float2(a2), f3 = __half22float2(a3);
    f[0] = f0.x; f[1] = f0.y; f[2] = f1.x; f[3] = f1.y;
    f[4] = f2.x; f[5] = f2.y; f[6] = f3.x; f[7] = f3.y;
}

// ---------------- fused gather(4 nodes/wave) + relu + LDS matmul ----------------
// Block = 4 waves = 16 nodes.
__global__ __launch_bounds__(256) void k_gmm(
        const int* __restrict__ rowptr, const int* __restrict__ col,
        const float* __restrict__ dinv, const float* __restrict__ b,
        const __half* __restrict__ hw_in, const float* __restrict__ W,
        __half* __restrict__ hw_out) {
    __shared__ float sW[64 * 64];
    __shared__ float sA[16 * 64];
    int t = threadIdx.x;
    const float4* W4 = (const float4*)W;
    float4* sW4 = (float4*)sW;
    for (int i = t; i < 1024; i += 256) sW4[i] = W4[i];
    __syncthreads();

    int wave = t >> 6, lane = t & 63;
    int quarter = lane >> 4, slot = (lane >> 3) & 1, sub = lane & 7;
    int i0 = blockIdx.x * 16 + wave * 4;
    int i = i0 + quarter;
    float di = dinv[i];
    int rs = rowptr[i], re = rowptr[i + 1];
    const uint4* hv = (const uint4*)hw_in;

    float f[8];
    gather2x4(col, hv, rs, re, slot, sub, f);

    // conv epilogue (fp32): r = relu(di*(f+self)+b)
    uint4 us = hv[(size_t)i * 8 + sub];
    float2 s0 = __half22float2(*(__half2*)&us.x);
    float2 s1 = __half22float2(*(__half2*)&us.y);
    float2 s2 = __half22float2(*(__half2*)&us.z);
    float2 s3 = __half22float2(*(__half2*)&us.w);
    float sf[8] = {s0.x, s0.y, s1.x, s1.y, s2.x, s2.y, s3.x, s3.y};
    float4 ba = ((const float4*)b)[sub * 2];
    float4 bb = ((const float4*)b)[sub * 2 + 1];
    float bf[8] = {ba.x, ba.y, ba.z, ba.w, bb.x, bb.y, bb.z, bb.w};
    if (slot == 0) {
        float r[8];
#pragma unroll
        for (int k = 0; k < 8; ++k) r[k] = fmaxf(fmaf(di, f[k] + sf[k], bf[k]), 0.f);
        *(float4*)&sA[(wave * 4 + quarter) * 64 + sub * 8]     = make_float4(r[0], r[1], r[2], r[3]);
        *(float4*)&sA[(wave * 4 + quarter) * 64 + sub * 8 + 4] = make_float4(r[4], r[5], r[6], r[7]);
    }

    // per-wave mm for all 4 nodes (same-wave LDS ordering; barrier above covers sW)
#pragma unroll
    for (int h = 0; h < 4; ++h) {
        const float4* sA4 = (const float4*)&sA[(wave * 4 + h) * 64];
        float sum = 0.f;
#pragma unroll
        for (int k4 = 0; k4 < 16; ++k4) {
            float4 a4 = sA4[k4];
            sum = fmaf(a4.x, sW[(k4 * 4 + 0) * 64 + lane], sum);
            sum = fmaf(a4.y, sW[(k4 * 4 + 1) * 64 + lane], sum);
            sum = fmaf(a4.z, sW[(k4 * 4 + 2) * 64 + lane], sum);
            sum = fmaf(a4.w, sW[(k4 * 4 + 3) * 64 + lane], sum);
        }
        hw_out[(size_t)(i0 + h) * 64 + lane] = __float2half_rn(sum * dinv[i0 + h]);
    }
}

// ---------------- layer-3 gather (4 nodes/wave; fp16 conv out) ----------------
__global__ __launch_bounds__(256) void k_gather3(
        const int* __restrict__ rowptr, const int* __restrict__ col,
        const float* __restrict__ dinv, const float* __restrict__ b,
        const __half* __restrict__ hw_in, __half* __restrict__ conv) {
    int t = threadIdx.x;
    int wave = t >> 6, lane = t & 63;
    int quarter = lane >> 4, slot = (lane >> 3) & 1, sub = lane & 7;
    int i = blockIdx.x * 16 + wave * 4 + quarter;
    float di = dinv[i];
    int rs = rowptr[i], re = rowptr[i + 1];
    const uint4* hv = (const uint4*)hw_in;

    float f[8];
    gather2x4(col, hv, rs, re, slot, sub, f);

    if (slot == 0) {
        uint4 us = hv[(size_t)i * 8 + sub];
        float2 s0 = __half22float2(*(__half2*)&us.x);
        float2 s1 = __half22float2(*(__half2*)&us.y);
        float2 s2 = __half22float2(*(__half2*)&us.z);
        float2 s3 = __half22float2(*(__half2*)&us.w);
        float sf[8] = {s0.x, s0.y, s1.x, s1.y, s2.x, s2.y, s3.x, s3.y};
        float4 ba = ((const float4*)b)[sub * 2];
        float4 bb = ((const float4*)b)[sub * 2 + 1];
        float bf[8] = {ba.x, ba.y, ba.z, ba.w, bb.x, bb.y, bb.z, bb.w};
        uint4 o;
        __half2* oh = (__half2*)&o;
#pragma unroll
        for (int c = 0; c < 4; ++c) {
            float r0 = fmaf(di, f[2 * c] + sf[2 * c], bf[2 * c]);
            float r1 = fmaf(di, f[2 * c + 1] + sf[2 * c + 1], bf[2 * c + 1]);
            oh[c] = __halves2half2(__float2half_rn(r0), __float2half_rn(r1));
        }
        ((uint4*)conv)[(size_t)i * 8 + sub] = o;
    }
}

// ---------------- segmented mean-pool (fp16 conv in) ----------------
__global__ __launch_bounds__(256) void k_pool(
        const __half* __restrict__ conv, const int* __restrict__ gstart,
        float* __restrict__ pooled) {
    int t = threadIdx.x;
    int wave = t >> 6, lane = t & 63;
    int g = blockIdx.x * 4 + wave;
    int n0 = gstart[g], n1 = gstart[g + 1];
    float acc = 0.f;
    for (int i = n0; i < n1; ++i) acc += __half2float(conv[(size_t)i * 64 + lane]);
    int n = n1 - n0;
    pooled[g * 64 + lane] = (n > 0) ? acc / (float)n : 0.f;
}

// ---------------- dense + softmax + threshold: 8 graphs per block ----------------
__global__ __launch_bounds__(256) void k_dense(
        const float* __restrict__ pooled, const float* __restrict__ Wd,
        const float* __restrict__ bd, float* __restrict__ out) {
    __shared__ float sp[8][64];
    __shared__ float red[8][4];
    int t = threadIdx.x;
    int g0 = blockIdx.x * 8;
    for (int idx = t; idx < 512; idx += 256) {
        int g = idx >> 6, k = idx & 63;
        sp[g][k] = pooled[(g0 + g) * 64 + k];
    }
    __syncthreads();

    float acc[8][8];
#pragma unroll
    for (int r = 0; r < 8; ++r) {
        float bv = bd[r * 256 + t];
#pragma unroll
        for (int g = 0; g < 8; ++g) acc[g][r] = bv;
    }
    for (int k = 0; k < 64; ++k) {
        float w[8];
#pragma unroll
        for (int r = 0; r < 8; ++r) w[r] = Wd[k * BIOPRINT + r * 256 + t];
#pragma unroll
        for (int g = 0; g < 8; ++g) {
            float h = sp[g][k];
#pragma unroll
            for (int r = 0; r < 8; ++r) acc[g][r] = fmaf(h, w[r], acc[g][r]);
        }
    }
    int wave = t >> 6, lane = t & 63;
    float gm[8];
#pragma unroll
    for (int g = 0; g < 8; ++g) {
        float m = acc[g][0];
#pragma unroll
        for (int r = 1; r < 8; ++r) m = fmaxf(m, acc[g][r]);
#pragma unroll
        for (int off = 32; off > 0; off >>= 1) m = fmaxf(m, __shfl_xor(m, off));
        if (lane == 0) red[g][wave] = m;
    }
    __syncthreads();
#pragma unroll
    for (int g = 0; g < 8; ++g)
        gm[g] = fmaxf(fmaxf(red[g][0], red[g][1]), fmaxf(red[g][2], red[g][3]));
    __syncthreads();
    float gs[8];
#pragma unroll
    for (int g = 0; g < 8; ++g) {
        float s = 0.f;
#pragma unroll
        for (int r = 0; r < 8; ++r) { acc[g][r] = expf(acc[g][r] - gm[g]); s += acc[g][r]; }
#pragma unroll
        for (int off = 32; off > 0; off >>= 1) s += __shfl_xor(s, off);
        if (lane == 0) red[g][wave] = s;
    }
    __syncthreads();
#pragma unroll
    for (int g = 0; g < 8; ++g)
        gs[g] = red[g][0] + red[g][1] + red[g][2] + red[g][3];
#pragma unroll
    for (int g = 0; g < 8; ++g)
#pragma unroll
        for (int r = 0; r < 8; ++r) {
            float p = acc[g][r] / gs[g];
            out[(size_t)(g0 + g) * BIOPRINT + r * 256 + t] = (p >= 0.5f) ? 1.0f : 0.0f;
        }
}

// ---------------- launch ----------------

extern "C" void kernel_launch(void* const* d_in, const int* in_sizes, int n_in,
                              void* d_out, int out_size, void* d_ws, size_t ws_size,
                              hipStream_t stream) {
    const float* x     = (const float*)d_in[0];
    const int*   ei    = (const int*)d_in[1];
    const int*   batch = (const int*)d_in[2];
    const float* W1 = (const float*)d_in[3];
    const float* b1 = (const float*)d_in[4];
    const float* W2 = (const float*)d_in[5];
    const float* b2 = (const float*)d_in[6];
    const float* W3 = (const float*)d_in[7];
    const float* b3 = (const float*)d_in[8];
    const float* Wd = (const float*)d_in[9];
    const float* bd = (const float*)d_in[10];
    float* out = (float*)d_out;

    const int* src = ei;
    const int* dst = ei + N_EDGES;

    char* ws = (char*)d_ws;
    size_t off = 0;
    auto alloc = [&](size_t bytes) {
        void* p = ws + off;
        off += (bytes + 255) & ~(size_t)255;
        return p;
    };
    int*    deg    = (int*)alloc(N_NODES * sizeof(int));
    float*  dinv   = (float*)alloc(N_NODES * sizeof(float));
    float*  pooled = (float*)alloc(N_GRAPHS * HIDDEN * sizeof(float));
    int*    rowptr = (int*)alloc((N_NODES + 1) * sizeof(int));
    int*    bsum   = (int*)alloc(128 * sizeof(int));
    int*    cursor = (int*)alloc(N_NODES * sizeof(int));
    int*    gstart = (int*)alloc((N_GRAPHS + 1) * sizeof(int));
    int*    col    = (int*)alloc((size_t)N_EDGES * sizeof(int));
    __half* bufA   = (__half*)alloc((size_t)N_NODES * HIDDEN * sizeof(__half));
    __half* bufB   = (__half*)alloc((size_t)N_NODES * HIDDEN * sizeof(__half));
    __half* conv   = (__half*)alloc((size_t)N_NODES * HIDDEN * sizeof(__half));

    hipMemsetAsync(deg, 0, N_NODES * sizeof(int), stream);

    k_deg<<<(N_EDGES + 255) / 256, 256, 0, stream>>>(dst, deg, N_EDGES);
    k_scan1<<<N_SCAN_BLOCKS, SCAN_BLK, 0, stream>>>(deg, rowptr, bsum, dinv, N_NODES);
    k_scan3<<<N_SCAN_BLOCKS + 2, SCAN_BLK, 0, stream>>>(rowptr, deg, bsum, cursor,
                                                        batch, gstart, N_NODES);
    for (int p = 0; p < 2; ++p) {
        k_fillp<<<(N_EDGES + 255) / 256, 256, 0, stream>>>(
            src, dst, cursor, col, p * FILL_SLICE, (p + 1) * FILL_SLICE, N_EDGES);
    }

    const int mm_grid  = N_NODES / 4;          // 25000
    const int g16_grid = N_NODES / 16;         // 6250 (16 nodes/block)
    k_mm<<<mm_grid, 256, 0, stream>>>(x, W1, dinv, bufA);
    k_gmm<<<g16_grid, 256, 0, stream>>>(rowptr, col, dinv, b1, bufA, W2, bufB);
    k_gmm<<<g16_grid, 256, 0, stream>>>(rowptr, col, dinv, b2, bufB, W3, bufA);
    k_gather3<<<g16_grid, 256, 0, stream>>>(rowptr, col, dinv, b3, bufA, conv);
    k_pool<<<N_GRAPHS / 4, 256, 0, stream>>>(conv, gstart, pooled);
    k_dense<<<N_GRAPHS / 8, 256, 0, stream>>>(pooled, Wd, bd, out);
}